// Round 10
// baseline (25.460 us; speedup 1.0000x reference)
//
#include <hip/hip_runtime.h>

// Depth-4 path signature, N=64, L=512, C=8. Output/batch:
// [sig1(8) | sig2(64) | sig3(512) | sig4(4096)] = 4680 f32.
//
// Single fused kernel, grid 256 = (batch n) x (k-quarter kq), 1024 thr = 16 waves.
// R10 vs R9: phase A is de-LDS'd (R9 model: LDS pipe ~10.8us was the
// bottleneck, phase A's 1024 broadcast ds_read_b128 = 48% of it).
//   * Each wave's 32-step dx window (256 floats) is loaded ONCE from global,
//     4 floats/lane (2 coalesced dwordx4 + diff). Per step, the 8 uniform
//     dd values come via v_readlane (VALU pipe, -> SGPR), not LDS.
//   * dk0/dk1 (uniform kq select of SGPR dd) folds to scalar cselect.
//   * dx LDS region dropped (-16KB); no staging phase; all else = R9:
//     slot lvl1-3 -> LDS | B: exclusive prefix fold | C: contributions ->
//     contrib[w] (no atomics) | strided reduce + stride-17 transpose ->
//     coalesced lvl4 stores; wave15 writes lvl1-3 (k-slice).

static constexpr int L = 512;
static constexpr int NC = 8;
static constexpr int NSEG = L - 1;                 // 511
static constexpr int SIG = 8 + 64 + 512 + 4096;    // 4680
static constexpr int SLOT = 592;                   // 8 + 64 + 520 (lvl3 stride 65)
static constexpr int CONTRIB = 16 * SLOT;          // 9472
static constexpr int TRANSO = CONTRIB + 16 * 1024; // 25856
static constexpr int LDSF = TRANSO + 64 * 17 + 16; // 26960 floats
static constexpr size_t LDS_BYTES = (size_t)LDSF * sizeof(float);  // ~105 KB

__device__ __forceinline__ float rdl(float v, int lane) {
    return __int_as_float(__builtin_amdgcn_readlane(__float_as_int(v), lane));
}

__device__ __forceinline__ float sel8(float d0, float d1, float d2, float d3,
                                      float d4, float d5, float d6, float d7,
                                      bool b0, bool b1, bool b2) {
    float x0 = b0 ? d1 : d0;
    float x1 = b0 ? d3 : d2;
    float x2 = b0 ? d5 : d4;
    float x3 = b0 ? d7 : d6;
    float y0 = b1 ? x1 : x0;
    float y1 = b1 ? x3 : x2;
    return b2 ? y1 : y0;
}

__global__ __launch_bounds__(1024)
void sig_rdl(const float* __restrict__ path, float* __restrict__ out) {
    extern __shared__ __align__(16) float lds[];
    const int tid = threadIdx.x;
    const int w = tid >> 6;          // wave = chunk 0..15
    const int lane = tid & 63;       // (i,j)
    const int i = lane >> 3;
    const int j = lane & 7;
    const int n = blockIdx.x >> 2;   // batch
    const int kq = blockIdx.x & 3;   // k-quarter: k = kq*2, kq*2+1
    const int ka0 = kq * 2, ka1 = ka0 + 1;

    // ---- per-lane dx window load (phase A data; no LDS) ----
    // wave w covers segments [32w, 32w+32); lane m holds dx floats
    // [256w + 4m .. +3]. dx[f] = path[f+8] - path[f], f < 4088 else 0.
    const float4* pv4 = reinterpret_cast<const float4*>(path + (size_t)n * (L * NC));
    const int base = w * 64 + lane;              // float4 index into dx
    const float4 pa = pv4[base];
    const float4 pb = pv4[min(base + 2, 1023)];
    float4 dxr;
    dxr.x = pb.x - pa.x;
    dxr.y = pb.y - pa.y;
    dxr.z = pb.z - pa.z;
    dxr.w = pb.w - pa.w;
    if (base >= 1022) dxr = make_float4(0.f, 0.f, 0.f, 0.f);  // seg 511 pad

    // ---------------- Phase A: chunk scan (readlane-fed) ----------------
    const bool ib0 = lane & 8, ib1 = lane & 16, ib2 = lane & 32;
    const bool jb0 = lane & 1, jb1 = lane & 2, jb2 = lane & 4;

    float s1 = 0.f, s2 = 0.f, s3a = 0.f, s3b = 0.f;
    float s3[8];
    float accA[8], accB[8];
#pragma unroll
    for (int k = 0; k < 8; ++k) {
        s3[k] = 0.f;
        accA[k] = 0.f;
        accB[k] = 0.f;
    }
    constexpr float c3 = 1.f / 6.f;
    constexpr float c4 = 1.f / 24.f;

#pragma unroll 8
    for (int s = 0; s < 32; ++s) {
        // 8 uniform dd values from lanes 2s (x4) and 2s+1 (x4)
        const int l0 = 2 * s, l1 = 2 * s + 1;
        const float d0 = rdl(dxr.x, l0), d1 = rdl(dxr.y, l0);
        const float d2 = rdl(dxr.z, l0), d3 = rdl(dxr.w, l0);
        const float d4 = rdl(dxr.x, l1), d5 = rdl(dxr.y, l1);
        const float d6 = rdl(dxr.z, l1), d7 = rdl(dxr.w, l1);

        const float di = sel8(d0, d1, d2, d3, d4, d5, d6, d7, ib0, ib1, ib2);
        const float dj = sel8(d0, d1, d2, d3, d4, d5, d6, d7, jb0, jb1, jb2);
        // uniform (block-level) k-pair selection: scalar cselect
        const float xa = (kq & 1) ? d2 : d0, xb = (kq & 1) ? d6 : d4;
        const float dk0 = (kq & 2) ? xb : xa;
        const float ya = (kq & 1) ? d3 : d1, yb = (kq & 1) ? d7 : d5;
        const float dk1 = (kq & 2) ? yb : ya;

        const float u = fmaf(s1, c3, di * c4);    // s1/6 + di/24
        float vv = fmaf(s1, dj * 0.5f, s2);       // s2 + s1*dj/2
        vv = fmaf(di * dj, c3, vv);               // + di*dj/6
        const float w_ = fmaf(s2, 0.5f, dj * u);  // s2/2 + dj*u

        const float Cc0 = fmaf(dk0, w_, s3a);     // uses OLD s3[ka0]
        const float Cc1 = fmaf(dk1, w_, s3b);

        accA[0] = fmaf(d0, Cc0, accA[0]);  accB[0] = fmaf(d0, Cc1, accB[0]);
        accA[1] = fmaf(d1, Cc0, accA[1]);  accB[1] = fmaf(d1, Cc1, accB[1]);
        accA[2] = fmaf(d2, Cc0, accA[2]);  accB[2] = fmaf(d2, Cc1, accB[2]);
        accA[3] = fmaf(d3, Cc0, accA[3]);  accB[3] = fmaf(d3, Cc1, accB[3]);
        accA[4] = fmaf(d4, Cc0, accA[4]);  accB[4] = fmaf(d4, Cc1, accB[4]);
        accA[5] = fmaf(d5, Cc0, accA[5]);  accB[5] = fmaf(d5, Cc1, accB[5]);
        accA[6] = fmaf(d6, Cc0, accA[6]);  accB[6] = fmaf(d6, Cc1, accB[6]);
        accA[7] = fmaf(d7, Cc0, accA[7]);  accB[7] = fmaf(d7, Cc1, accB[7]);
        s3[0] = fmaf(d0, vv, s3[0]);
        s3[1] = fmaf(d1, vv, s3[1]);
        s3[2] = fmaf(d2, vv, s3[2]);
        s3[3] = fmaf(d3, vv, s3[3]);
        s3[4] = fmaf(d4, vv, s3[4]);
        s3[5] = fmaf(d5, vv, s3[5]);
        s3[6] = fmaf(d6, vv, s3[6]);
        s3[7] = fmaf(d7, vv, s3[7]);

        s3a = fmaf(dk0, vv, s3a);
        s3b = fmaf(dk1, vv, s3b);
        s2 = fmaf(dj, fmaf(di, 0.5f, s1), s2);
        s1 += di;
    }

    // write chunk lvl1-3 to LDS slot w; lvl3 layout [t1*65 + t2*8 + t3]
    {
        float* sp = lds + w * SLOT;
        if (j == 0) sp[i] = s1;
        sp[8 + i * 8 + j] = s2;
        float* s3p = sp + 72 + i * 65 + j * 8;
#pragma unroll
        for (int k = 0; k < 8; ++k) s3p[k] = s3[k];
    }
    __syncthreads();

    // ---------------- Phase B: exclusive prefix fold (Chen, lvl1-3) ------
    float a1 = 0.f, a2 = 0.f, a3A = 0.f, a3B = 0.f;
    {
        const float* bp = lds;
        for (int b = 0; b < w; ++b, bp += SLOT) {
            const float b1i = bp[i], b1j = bp[j];
            const float b1k0 = bp[ka0], b1k1 = bp[ka1];
            const float b2ij = bp[8 + i * 8 + j];
            const float b2jk0 = bp[8 + j * 8 + ka0];
            const float b2jk1 = bp[8 + j * 8 + ka1];
            const float b3a = bp[72 + i * 65 + j * 8 + ka0];
            const float b3b = bp[72 + i * 65 + j * 8 + ka1];
            a3A = fmaf(a2, b1k0, fmaf(a1, b2jk0, a3A + b3a));
            a3B = fmaf(a2, b1k1, fmaf(a1, b2jk1, a3B + b3b));
            a2 = fmaf(a1, b1j, a2 + b2ij);
            a1 += b1i;
        }
    }

    // ---------------- Phase C: contribution -> contrib[w][c*64+lane] -----
    {
        const float* cp = lds + w * SLOT;
        float* cb = lds + CONTRIB + w * 1024 + lane;
#pragma unroll
        for (int l = 0; l < 8; ++l) {
            const float b1l = cp[l];
            const float b2a = cp[8 + ka0 * 8 + l];
            const float b2b = cp[8 + ka1 * 8 + l];
            const float b3a = cp[72 + j * 65 + ka0 * 8 + l];
            const float b3b = cp[72 + j * 65 + ka1 * 8 + l];
            const float va = fmaf(a3A, b1l, fmaf(a2, b2a, fmaf(a1, b3a, accA[l])));
            const float vb = fmaf(a3B, b1l, fmaf(a2, b2b, fmaf(a1, b3b, accB[l])));
            cb[l * 64] = va;          // c = 0*8 + l
            cb[(8 + l) * 64] = vb;    // c = 1*8 + l
        }
    }

    // ---------------- final lvl1-3 (wave 15; lvl3 k-slice per block) -----
    if (w == 15) {
        const float* bp = lds + 15 * SLOT;
        const float b1i = bp[i], b1j = bp[j];
        const float b1k0 = bp[ka0], b1k1 = bp[ka1];
        const float b2ij = bp[8 + i * 8 + j];
        const float b2jk0 = bp[8 + j * 8 + ka0];
        const float b2jk1 = bp[8 + j * 8 + ka1];
        const float b3a = bp[72 + i * 65 + j * 8 + ka0];
        const float b3b = bp[72 + i * 65 + j * 8 + ka1];
        a3A = fmaf(a2, b1k0, fmaf(a1, b2jk0, a3A + b3a));
        a3B = fmaf(a2, b1k1, fmaf(a1, b2jk1, a3B + b3b));
        a2 = fmaf(a1, b1j, a2 + b2ij);
        a1 += b1i;
        float* o = out + (size_t)n * SIG;
        o[72 + i * 64 + j * 8 + ka0] = a3A;
        o[72 + i * 64 + j * 8 + ka1] = a3B;
        if (kq == 0) {
            o[8 + i * 8 + j] = a2;
            if (j == 0) o[i] = a1;
        }
    }
    __syncthreads();

    // ---------------- reduce over w, transpose, coalesced store ----------
    {
        float s = 0.f;
        const float* c0 = lds + CONTRIB + tid;
#pragma unroll
        for (int ww = 0; ww < 16; ++ww) s += c0[ww * 1024];
        lds[TRANSO + (tid & 63) * 17 + (tid >> 6)] = s;
    }
    __syncthreads();
    if (tid < 256) {
        const int lp = tid >> 2, cq = tid & 3;
        const float* tp = lds + TRANSO + lp * 17 + cq * 4;
        float4 r;
        r.x = tp[0]; r.y = tp[1]; r.z = tp[2]; r.w = tp[3];
        *reinterpret_cast<float4*>(out + (size_t)n * SIG + 584 + lp * 64 + kq * 16 + cq * 4) = r;
    }
}

extern "C" void kernel_launch(void* const* d_in, const int* in_sizes, int n_in,
                              void* d_out, int out_size, void* d_ws, size_t ws_size,
                              hipStream_t stream) {
    const float* path = (const float*)d_in[0];
    float* out = (float*)d_out;
    (void)hipFuncSetAttribute((const void*)sig_rdl,
                              hipFuncAttributeMaxDynamicSharedMemorySize,
                              (int)LDS_BYTES);
    // 64 batches x 4 k-quarters = 256 blocks (1 per CU), 1024 threads each
    sig_rdl<<<256, 1024, LDS_BYTES, stream>>>(path, out);
}

// Round 11
// 20.950 us; speedup vs baseline: 1.2153x; 1.2153x over previous
//
#include <hip/hip_runtime.h>

// Depth-4 path signature, N=64, L=512, C=8. Output/batch:
// [sig1(8) | sig2(64) | sig3(512) | sig4(4096)] = 4680 f32.
//
// R11 = R9 (proven 20.4us) + phase-A software pipeline (depth-1 prefetch).
// R10's readlane feed regressed (SGPR operands -> v_mov blowup); LDS
// broadcast reads are cheap (~4-6cy). The remaining gap vs the ~12.5us
// model is exposed per-step LDS latency in lockstep waves -> prefetch
// step s+1's two float4s into named regs before computing step s.
//
// Single fused kernel, grid 256 = (batch n) x (k-quarter kq), 1024 thr = 16 waves.
//   stage dx->LDS | A: wave w scans chunk w (32 segs, lvl1-3 full + lvl4 acc
//   for k-pair, regs, prefetched) | slot lvl1-3 -> LDS | B: exclusive prefix
//   fold (serial, 9 indep reads/fold) | C: D4 = B4 + A3*B1[l] + A2*B2[k,l] +
//   A1*B3[j,k,l] -> contrib[w] (no atomics) | strided reduce + stride-17
//   transpose -> coalesced lvl4 stores; wave15 writes lvl1-3 (k-slice).

static constexpr int L = 512;
static constexpr int NC = 8;
static constexpr int NSEG = L - 1;                 // 511
static constexpr int SIG = 8 + 64 + 512 + 4096;    // 4680
static constexpr int DXF = NSEG * NC;              // 4088 floats
static constexpr int SLOTOFF = DXF;                // 4088
static constexpr int SLOT = 592;                   // 8 + 64 + 520 (lvl3 stride 65)
static constexpr int CONTRIB = SLOTOFF + 16 * SLOT;  // 13560
static constexpr int TRANSO = CONTRIB + 16 * 1024;   // 29944
static constexpr int LDSF = TRANSO + 64 * 17 + 16;   // 31048 floats
static constexpr size_t LDS_BYTES = (size_t)LDSF * sizeof(float);  // ~121 KB

__device__ __forceinline__ float sel8(float d0, float d1, float d2, float d3,
                                      float d4, float d5, float d6, float d7,
                                      bool b0, bool b1, bool b2) {
    float x0 = b0 ? d1 : d0;
    float x1 = b0 ? d3 : d2;
    float x2 = b0 ? d5 : d4;
    float x3 = b0 ? d7 : d6;
    float y0 = b1 ? x1 : x0;
    float y1 = b1 ? x3 : x2;
    return b2 ? y1 : y0;
}

__global__ __launch_bounds__(1024)
void sig_pipe(const float* __restrict__ path, float* __restrict__ out) {
    extern __shared__ __align__(16) float lds[];
    const int tid = threadIdx.x;
    const int w = tid >> 6;          // wave = chunk 0..15
    const int lane = tid & 63;       // (i,j)
    const int i = lane >> 3;
    const int j = lane & 7;
    const int n = blockIdx.x >> 2;   // batch
    const int kq = blockIdx.x & 3;   // k-quarter: k = kq*2, kq*2+1
    const int ka0 = kq * 2, ka1 = ka0 + 1;

    // ---- stage dx into LDS (independent parallel loads) ----
    {
        const float4* pv = reinterpret_cast<const float4*>(path + (size_t)n * (L * NC));
        if (tid < DXF / 4) {  // 1022 float4 diffs
            const float4 a = pv[tid];
            const float4 b = pv[tid + 2];
            *reinterpret_cast<float4*>(&lds[tid * 4]) =
                make_float4(b.x - a.x, b.y - a.y, b.z - a.z, b.w - a.w);
        }
    }
    __syncthreads();

    // ---------------- Phase A: chunk scan (LDS-fed, sw-pipelined) --------
    const int seg0 = w * 32;

    const bool ib0 = lane & 8, ib1 = lane & 16, ib2 = lane & 32;
    const bool jb0 = lane & 1, jb1 = lane & 2, jb2 = lane & 4;
    const bool kb0 = kq & 1, kb1 = kq & 2;

    float s1 = 0.f, s2 = 0.f, s3a = 0.f, s3b = 0.f;
    float s3[8];
    float accA[8], accB[8];
#pragma unroll
    for (int k = 0; k < 8; ++k) {
        s3[k] = 0.f;
        accA[k] = 0.f;
        accB[k] = 0.f;
    }
    constexpr float c3 = 1.f / 6.f;
    constexpr float c4 = 1.f / 24.f;

    const float* dbase = lds + seg0 * 8;
    // NOTE: lds holds 511 segments; wave 15 reads segs 480..511 where seg 511
    // does not exist. Guard the last read of the last wave by clamping: seg
    // 511's dd would be garbage; handle via len check below.
    const int len = min(32, NSEG - seg0);           // 32 for w<15, 31 for w==15

    float4 A0 = *reinterpret_cast<const float4*>(dbase);
    float4 B0 = *reinterpret_cast<const float4*>(dbase + 4);
#pragma unroll 8
    for (int s = 0; s < 32; ++s) {
        // depth-1 prefetch of next step's data (address static per s)
        float4 A1, B1;
        if (s < 31) {
            A1 = *reinterpret_cast<const float4*>(dbase + (s + 1) * 8);
            B1 = *reinterpret_cast<const float4*>(dbase + (s + 1) * 8 + 4);
        }
        if (s < len) {
            const float d0 = A0.x, d1 = A0.y, d2 = A0.z, d3 = A0.w;
            const float d4 = B0.x, d5 = B0.y, d6 = B0.z, d7 = B0.w;

            const float di = sel8(d0, d1, d2, d3, d4, d5, d6, d7, ib0, ib1, ib2);
            const float dj = sel8(d0, d1, d2, d3, d4, d5, d6, d7, jb0, jb1, jb2);
            const float xa = kb0 ? d2 : d0, xb = kb0 ? d6 : d4;
            const float dk0 = kb1 ? xb : xa;
            const float ya = kb0 ? d3 : d1, yb = kb0 ? d7 : d5;
            const float dk1 = kb1 ? yb : ya;

            const float u = fmaf(s1, c3, di * c4);    // s1/6 + di/24
            float vv = fmaf(s1, dj * 0.5f, s2);       // s2 + s1*dj/2
            vv = fmaf(di * dj, c3, vv);               // + di*dj/6
            const float w_ = fmaf(s2, 0.5f, dj * u);  // s2/2 + dj*u

            const float Cc0 = fmaf(dk0, w_, s3a);     // uses OLD s3[ka0]
            const float Cc1 = fmaf(dk1, w_, s3b);

            accA[0] = fmaf(d0, Cc0, accA[0]);  accB[0] = fmaf(d0, Cc1, accB[0]);
            accA[1] = fmaf(d1, Cc0, accA[1]);  accB[1] = fmaf(d1, Cc1, accB[1]);
            accA[2] = fmaf(d2, Cc0, accA[2]);  accB[2] = fmaf(d2, Cc1, accB[2]);
            accA[3] = fmaf(d3, Cc0, accA[3]);  accB[3] = fmaf(d3, Cc1, accB[3]);
            accA[4] = fmaf(d4, Cc0, accA[4]);  accB[4] = fmaf(d4, Cc1, accB[4]);
            accA[5] = fmaf(d5, Cc0, accA[5]);  accB[5] = fmaf(d5, Cc1, accB[5]);
            accA[6] = fmaf(d6, Cc0, accA[6]);  accB[6] = fmaf(d6, Cc1, accB[6]);
            accA[7] = fmaf(d7, Cc0, accA[7]);  accB[7] = fmaf(d7, Cc1, accB[7]);
            s3[0] = fmaf(d0, vv, s3[0]);
            s3[1] = fmaf(d1, vv, s3[1]);
            s3[2] = fmaf(d2, vv, s3[2]);
            s3[3] = fmaf(d3, vv, s3[3]);
            s3[4] = fmaf(d4, vv, s3[4]);
            s3[5] = fmaf(d5, vv, s3[5]);
            s3[6] = fmaf(d6, vv, s3[6]);
            s3[7] = fmaf(d7, vv, s3[7]);

            s3a = fmaf(dk0, vv, s3a);
            s3b = fmaf(dk1, vv, s3b);
            s2 = fmaf(dj, fmaf(di, 0.5f, s1), s2);
            s1 += di;
        }
        if (s < 31) { A0 = A1; B0 = B1; }
    }

    // write chunk lvl1-3 to LDS slot w; lvl3 layout [t1*65 + t2*8 + t3]
    {
        float* sp = lds + SLOTOFF + w * SLOT;
        if (j == 0) sp[i] = s1;
        sp[8 + i * 8 + j] = s2;
        float* s3p = sp + 72 + i * 65 + j * 8;
#pragma unroll
        for (int k = 0; k < 8; ++k) s3p[k] = s3[k];
    }
    __syncthreads();

    // ---------------- Phase B: exclusive prefix fold (Chen, lvl1-3) ------
    float a1 = 0.f, a2 = 0.f, a3A = 0.f, a3B = 0.f;
    {
        const float* bp = lds + SLOTOFF;
        for (int b = 0; b < w; ++b, bp += SLOT) {
            const float b1i = bp[i], b1j = bp[j];
            const float b1k0 = bp[ka0], b1k1 = bp[ka1];
            const float b2ij = bp[8 + i * 8 + j];
            const float b2jk0 = bp[8 + j * 8 + ka0];
            const float b2jk1 = bp[8 + j * 8 + ka1];
            const float b3a = bp[72 + i * 65 + j * 8 + ka0];
            const float b3b = bp[72 + i * 65 + j * 8 + ka1];
            a3A = fmaf(a2, b1k0, fmaf(a1, b2jk0, a3A + b3a));
            a3B = fmaf(a2, b1k1, fmaf(a1, b2jk1, a3B + b3b));
            a2 = fmaf(a1, b1j, a2 + b2ij);
            a1 += b1i;
        }
    }

    // ---------------- Phase C: contribution -> contrib[w][c*64+lane] -----
    {
        const float* cp = lds + SLOTOFF + w * SLOT;
        float* cb = lds + CONTRIB + w * 1024 + lane;
#pragma unroll
        for (int l = 0; l < 8; ++l) {
            const float b1l = cp[l];
            const float b2a = cp[8 + ka0 * 8 + l];
            const float b2b = cp[8 + ka1 * 8 + l];
            const float b3a = cp[72 + j * 65 + ka0 * 8 + l];
            const float b3b = cp[72 + j * 65 + ka1 * 8 + l];
            const float va = fmaf(a3A, b1l, fmaf(a2, b2a, fmaf(a1, b3a, accA[l])));
            const float vb = fmaf(a3B, b1l, fmaf(a2, b2b, fmaf(a1, b3b, accB[l])));
            cb[l * 64] = va;          // c = 0*8 + l
            cb[(8 + l) * 64] = vb;    // c = 1*8 + l
        }
    }

    // ---------------- final lvl1-3 (wave 15; lvl3 k-slice per block) -----
    if (w == 15) {
        const float* bp = lds + SLOTOFF + 15 * SLOT;
        const float b1i = bp[i], b1j = bp[j];
        const float b1k0 = bp[ka0], b1k1 = bp[ka1];
        const float b2ij = bp[8 + i * 8 + j];
        const float b2jk0 = bp[8 + j * 8 + ka0];
        const float b2jk1 = bp[8 + j * 8 + ka1];
        const float b3a = bp[72 + i * 65 + j * 8 + ka0];
        const float b3b = bp[72 + i * 65 + j * 8 + ka1];
        a3A = fmaf(a2, b1k0, fmaf(a1, b2jk0, a3A + b3a));
        a3B = fmaf(a2, b1k1, fmaf(a1, b2jk1, a3B + b3b));
        a2 = fmaf(a1, b1j, a2 + b2ij);
        a1 += b1i;
        float* o = out + (size_t)n * SIG;
        o[72 + i * 64 + j * 8 + ka0] = a3A;
        o[72 + i * 64 + j * 8 + ka1] = a3B;
        if (kq == 0) {
            o[8 + i * 8 + j] = a2;
            if (j == 0) o[i] = a1;
        }
    }
    __syncthreads();

    // ---------------- reduce over w, transpose, coalesced store ----------
    {
        float s = 0.f;
        const float* c0 = lds + CONTRIB + tid;
#pragma unroll
        for (int ww = 0; ww < 16; ++ww) s += c0[ww * 1024];
        lds[TRANSO + (tid & 63) * 17 + (tid >> 6)] = s;
    }
    __syncthreads();
    if (tid < 256) {
        const int lp = tid >> 2, cq = tid & 3;
        const float* tp = lds + TRANSO + lp * 17 + cq * 4;
        float4 r;
        r.x = tp[0]; r.y = tp[1]; r.z = tp[2]; r.w = tp[3];
        *reinterpret_cast<float4*>(out + (size_t)n * SIG + 584 + lp * 64 + kq * 16 + cq * 4) = r;
    }
}

extern "C" void kernel_launch(void* const* d_in, const int* in_sizes, int n_in,
                              void* d_out, int out_size, void* d_ws, size_t ws_size,
                              hipStream_t stream) {
    const float* path = (const float*)d_in[0];
    float* out = (float*)d_out;
    (void)hipFuncSetAttribute((const void*)sig_pipe,
                              hipFuncAttributeMaxDynamicSharedMemorySize,
                              (int)LDS_BYTES);
    // 64 batches x 4 k-quarters = 256 blocks (1 per CU), 1024 threads each
    sig_pipe<<<256, 1024, LDS_BYTES, stream>>>(path, out);
}